// Round 1
// baseline (865.411 us; speedup 1.0000x reference)
//
#include <hip/hip_runtime.h>
#include <math.h>

// CTC batch cost (Keras ctc_batch_cost semantics, full lengths).
// B=64 batch, T=2048 frames, C=128 classes (blank=C-1), L=256 labels, S=2L+1=513.
// Serial recurrence over T; one block per batch element, alpha in LDS.

#define B_ 64
#define T_ 2048
#define C_ 128
#define L_ 256
#define S_ 513
#define BLANK_ (C_ - 1)
#define NEG_ (-1e30f)
#define EPS_ (1e-7f)

__launch_bounds__(512, 1)
__global__ void ctc_loss_kernel(const int* __restrict__ y_true,
                                const float* __restrict__ y_pred,
                                float* __restrict__ out) {
    const int b = blockIdx.x;
    const int tid = threadIdx.x;

    // Double-buffered alpha and per-frame log-probs.
    __shared__ float alpha[2][S_];
    __shared__ float lp[2][C_];

    // Per-thread extended-label metadata (state s = tid; tid 0 also owns s=512).
    // ext[s] = blank for even s, labels[s/2] for odd s.
    // skip[s] = odd s >= 3 && labels[s/2] != labels[s/2-1].
    int e0 = BLANK_;
    bool k0 = false;
    if (tid & 1) {
        const int li = tid >> 1;
        const int lab = y_true[b * L_ + li];
        e0 = lab;
        if (tid >= 3) k0 = (lab != y_true[b * L_ + li - 1]);
    }

    const float* __restrict__ base = y_pred + (size_t)b * T_ * C_;

    // t = 0: compute lp[0], prefetch row t=1 into register.
    float pre = 0.0f;
    if (tid < C_) {
        lp[0][tid] = __logf(base[tid] + EPS_);
        pre = base[C_ + tid];
    }
    __syncthreads();

    // alpha0: states 0 and 1 get lp of their ext label, rest NEG.
    alpha[0][tid] = (tid < 2) ? lp[0][e0] : NEG_;
    if (tid == 0) alpha[0][512] = NEG_;

    int cur = 0;
    for (int t = 1; t < T_; ++t) {
        const int nb = t & 1;
        // Phase A: materialize lp for this step from the prefetched row,
        // then issue the prefetch for t+1.
        if (tid < C_) {
            lp[nb][tid] = __logf(pre + EPS_);
            if (t + 1 < T_) pre = base[(size_t)(t + 1) * C_ + tid];
        }
        __syncthreads();
        // Phase B: alpha update. Buffers alternate, so the single barrier
        // above separates every conflicting read/write pair across iters.
        const float* __restrict__ ac = alpha[cur];
        float* __restrict__ an = alpha[cur ^ 1];
        const float* __restrict__ lpt = lp[nb];
        {
            const float a  = ac[tid];
            const float b1 = (tid >= 1) ? ac[tid - 1] : NEG_;
            const float c2 = k0 ? ac[tid - 2] : NEG_;
            const float m = fmaxf(fmaxf(a, b1), c2);
            const float v = m + __logf(__expf(a - m) + __expf(b1 - m) + __expf(c2 - m));
            an[tid] = v + lpt[e0];
        }
        if (tid == 0) {
            // state s = 512: ext=blank, no skip.
            const float a  = ac[512];
            const float b1 = ac[511];
            const float m = fmaxf(a, b1);
            const float v = m + __logf(__expf(a - m) + __expf(b1 - m));
            an[512] = v + lpt[BLANK_];
        }
        cur ^= 1;
    }
    __syncthreads();

    if (tid == 0) {
        const float a  = alpha[cur][512];
        const float b1 = alpha[cur][511];
        const float m = fmaxf(a, b1);
        out[b] = -(m + __logf(__expf(a - m) + __expf(b1 - m)));
    }
}

extern "C" void kernel_launch(void* const* d_in, const int* in_sizes, int n_in,
                              void* d_out, int out_size, void* d_ws, size_t ws_size,
                              hipStream_t stream) {
    const int* y_true = (const int*)d_in[0];
    const float* y_pred = (const float*)d_in[1];
    float* out = (float*)d_out;
    ctc_loss_kernel<<<B_, 512, 0, stream>>>(y_true, y_pred, out);
}

// Round 3
// 817.935 us; speedup vs baseline: 1.0580x; 1.0580x over previous
//
#include <hip/hip_runtime.h>

// CTC batch cost (Keras ctc_batch_cost, full lengths).
// B=64, T=2048, C=128 (blank=127), L=256, S=513.
// One block per batch element; 128 threads (2 waves); thread tid owns states
// 4*tid .. 4*tid+3 in REGISTERS (tid 127 also owns state 512).
// Cross-lane per step: only neighbor's a3 (state 4*tid-1) -> one __shfl_up;
// wave0->wave1 crossing via one double-buffered LDS float (1 barrier/step).
// All math in log2 domain (v_exp_f32/v_log_f32 are base-2 native); known-max
// trick (max/med3/min, exp2(0)=1) cuts one exp per LSE.
// y_pred rows prefetched 8 steps ahead in a register circular buffer.
// NOTE: use exp2f (OCML -> single v_exp_f32) and __log2f (HIP intrinsic ->
// v_log_f32); __exp2f does NOT exist in HIP and collides with glibc macros.

#define B_ 64
#define T_ 2048
#define C_ 128
#define L_ 256
#define BLANK_ (C_ - 1)
#define NEGF (-1e30f)
#define EPSF (1e-7f)
#define LN2F 0.69314718055994530942f
#define PF_ 8  // prefetch depth == unroll factor (T_-PF_ divisible by PF_)

__launch_bounds__(128, 1)
__global__ void ctc_loss_kernel(const int* __restrict__ y_true,
                                const float* __restrict__ y_pred,
                                float* __restrict__ out) {
    const int b = blockIdx.x;
    const int tid = threadIdx.x;  // 0..127
    __shared__ float bnd[2];

    const int* __restrict__ lab = y_true + b * L_;
    // ext labels of this lane's odd states 4t+1, 4t+3:
    const int e1 = lab[2 * tid];
    const int e3 = lab[2 * tid + 1];
    // skip flags (odd s>=3 with label != label two back):
    const bool k1 = (tid >= 1) && (e1 != lab[2 * tid - 1]);
    const bool k3 = (e3 != e1);

    const float* __restrict__ base = y_pred + (size_t)b * (T_ * C_);

    // Register circular prefetch of the 3 per-lane y_pred values per row.
    float qb[PF_], q1[PF_], q3[PF_];
#pragma unroll
    for (int r = 0; r < PF_; ++r) {
        const float* __restrict__ row = base + r * C_;
        qb[r] = row[BLANK_];
        q1[r] = row[e1];
        q3[r] = row[e3];
    }

    // alphas (log2 domain): states 4tid..4tid+3, plus 512 on tid 127.
    float a0, a1v, a2v, a3v, a4v;
    {
        const float lpb = __log2f(qb[0] + EPSF);
        const float lp1 = __log2f(q1[0] + EPSF);
        a0  = (tid == 0) ? lpb : NEGF;  // state 0 (blank)
        a1v = (tid == 0) ? lp1 : NEGF;  // state 1 (label 0)
        a2v = NEGF; a3v = NEGF; a4v = NEGF;
        const float* __restrict__ row = base + PF_ * C_;
        qb[0] = row[BLANK_]; q1[0] = row[e1]; q3[0] = row[e3];
    }

    auto step = [&](const int R, const int t) {
        // publish state 255 (wave0 lane63 a3) for wave1 lane0
        if (tid == 63) bnd[t & 1] = a3v;
        // lp for this step (loads issued PF_ steps ago)
        const float lpb = __log2f(qb[R] + EPSF);
        const float lp1 = __log2f(q1[R] + EPSF);
        const float lp3 = __log2f(q3[R] + EPSF);
        // refill slot R with row t+PF_ (clamped; tail rows redundant, harmless)
        int tn = t + PF_; if (tn > T_ - 1) tn = T_ - 1;
        const float* __restrict__ row = base + (size_t)tn * C_;
        const float nqb = row[BLANK_], nq1 = row[e1], nq3 = row[e3];
        __syncthreads();
        float up3 = __shfl_up(a3v, 1);          // neighbor state 4tid-1
        if (tid == 64) up3 = bnd[t & 1];        // wave boundary
        if (tid == 0)  up3 = NEGF;              // state -1
        // state 4tid (even, blank): lse2(a0, up3) + lpb
        const float m0 = fmaxf(a0, up3);
        const float n0 = m0 + __log2f(1.0f + exp2f(fminf(a0, up3) - m0)) + lpb;
        // state 4tid+1 (odd): lse3(a1, a0, k1 ? up3 : NEG) + lp1
        const float z1 = k1 ? up3 : NEGF;
        const float m1 = fmaxf(fmaxf(a1v, a0), z1);
        const float p1 = __builtin_amdgcn_fmed3f(a1v, a0, z1);
        const float w1 = fminf(fminf(a1v, a0), z1);
        const float n1 = m1 + __log2f(1.0f + exp2f(p1 - m1) + exp2f(w1 - m1)) + lp1;
        // state 4tid+2 (even, blank): lse2(a2, a1) + lpb
        const float m2 = fmaxf(a2v, a1v);
        const float n2 = m2 + __log2f(1.0f + exp2f(fminf(a2v, a1v) - m2)) + lpb;
        // state 4tid+3 (odd): lse3(a3, a2, k3 ? a1 : NEG) + lp3
        const float z3 = k3 ? a1v : NEGF;
        const float m3 = fmaxf(fmaxf(a3v, a2v), z3);
        const float p3 = __builtin_amdgcn_fmed3f(a3v, a2v, z3);
        const float w3 = fminf(fminf(a3v, a2v), z3);
        const float n3 = m3 + __log2f(1.0f + exp2f(p3 - m3) + exp2f(w3 - m3)) + lp3;
        // state 512 (even, blank; meaningful on tid 127 only): lse2(a4, a3) + lpb
        const float m4 = fmaxf(a4v, a3v);
        const float n4 = m4 + __log2f(1.0f + exp2f(fminf(a4v, a3v) - m4)) + lpb;
        a0 = n0; a1v = n1; a2v = n2; a3v = n3; a4v = n4;
        qb[R] = nqb; q1[R] = nq1; q3[R] = nq3;
    };

#pragma unroll
    for (int t = 1; t < PF_; ++t) step(t, t);

    for (int tb = PF_; tb < T_; tb += PF_) {
#pragma unroll
        for (int j = 0; j < PF_; ++j) step(j, tb + j);
    }

    if (tid == 127) {
        // loss = -logaddexp(alpha[512], alpha[511]) (natural log)
        const float m = fmaxf(a4v, a3v);
        const float l2 = m + __log2f(1.0f + exp2f(fminf(a4v, a3v) - m));
        out[b] = -LN2F * l2;
    }
}

extern "C" void kernel_launch(void* const* d_in, const int* in_sizes, int n_in,
                              void* d_out, int out_size, void* d_ws, size_t ws_size,
                              hipStream_t stream) {
    const int* y_true = (const int*)d_in[0];
    const float* y_pred = (const float*)d_in[1];
    float* out = (float*)d_out;
    ctc_loss_kernel<<<B_, 128, 0, stream>>>(y_true, y_pred, out);
}